// Round 1
// baseline (1253.736 us; speedup 1.0000x reference)
//
#include <hip/hip_runtime.h>

#define NN 100000
#define DD 512
#define HH 256
#define KNB 5

typedef __attribute__((ext_vector_type(8))) short short8v;
typedef __attribute__((ext_vector_type(4))) short short4v;
typedef __attribute__((ext_vector_type(4))) float float4v;

static __device__ __forceinline__ float bf2f(unsigned short u) {
  union { unsigned int i; float f; } c;
  c.i = ((unsigned int)u) << 16;
  return c.f;
}
static __device__ __forceinline__ unsigned short f2bf(float f) {
  union { float f; unsigned int i; } c;
  c.f = f;
  unsigned int u = c.i;
  u += 0x7FFFu + ((u >> 16) & 1u);   // round-to-nearest-even
  return (unsigned short)(u >> 16);
}

// fp32 -> bf16 weight conversion (n4 = count/4)
__global__ void cvt_kernel(const float* __restrict__ src, short* __restrict__ dst, int n4) {
  int i = blockIdx.x * blockDim.x + threadIdx.x;
  if (i < n4) {
    float4 v = reinterpret_cast<const float4*>(src)[i];
    short4v o;
    o[0] = (short)f2bf(v.x); o[1] = (short)f2bf(v.y);
    o[2] = (short)f2bf(v.z); o[3] = (short)f2bf(v.w);
    reinterpret_cast<short4v*>(dst)[i] = o;
  }
}

// NT GEMM: C[i][j] = sum_k A[i][k] * B[j][k] + bias[j] (+ epilogue)
// AMODE 0: A fp32 [NN][KD]   (input projection from x)
// AMODE 1: A bf16 [NN][HH]   (hidden-to-hidden)
// AMODE 2: A[i] = mean_j t[nbr[i*5+j]]  (gather-mean fused, from Tadd bf16)
// EPI 0: store bf16 (bias only)
// EPI 1: v += t + slf, store bf16
// EPI 2: v += t + slf, out = relu(v)*0.5   (fp32 write)
// EPI 3: v += t + slf, out += relu(v)*0.5  (fp32 rmw)
template<int KD, int AMODE, int EPI>
__global__ __launch_bounds__(256) void gemm_k(
    const float* __restrict__ Af, const short* __restrict__ Ab,
    const short* __restrict__ Bw, const float* __restrict__ bias,
    short* __restrict__ Cb, float* __restrict__ Cf,
    const short* __restrict__ Tadd, const short* __restrict__ Sadd,
    const int* __restrict__ nbr)
{
  constexpr int BM = 128;
  constexpr int BK = 64;
  constexpr int LDR = BK + 8;  // +16B pad per row: 2-way bank alias only (free)
  __shared__ short As[BM * LDR];
  __shared__ short Bs[128 * LDR];

  const int tid = threadIdx.x;
  const int lane = tid & 63;
  const int wave = tid >> 6;
  const int wr = wave >> 1, wc = wave & 1;
  const int row0 = blockIdx.x * BM;
  const int bn0 = blockIdx.y * 128;

  float4v acc[4][4];
#pragma unroll
  for (int m = 0; m < 4; ++m)
#pragma unroll
    for (int n = 0; n < 4; ++n) acc[m][n] = (float4v)0.f;

  for (int k0 = 0; k0 < KD; k0 += BK) {
    // ---- stage A tile [BM][BK] ----
    if constexpr (AMODE == 0) {
#pragma unroll
      for (int e = tid; e < BM * (BK / 4); e += 256) {
        int r = e >> 4, c4 = e & 15;
        int rg = row0 + r;
        float4 v = make_float4(0.f, 0.f, 0.f, 0.f);
        if (rg < NN) v = *reinterpret_cast<const float4*>(Af + (size_t)rg * KD + k0 + c4 * 4);
        short4v o;
        o[0] = (short)f2bf(v.x); o[1] = (short)f2bf(v.y);
        o[2] = (short)f2bf(v.z); o[3] = (short)f2bf(v.w);
        *reinterpret_cast<short4v*>(&As[r * LDR + c4 * 4]) = o;
      }
    } else if constexpr (AMODE == 1) {
#pragma unroll
      for (int e = tid; e < BM * (BK / 8); e += 256) {
        int r = e >> 3, c8 = e & 7;
        int rg = row0 + r;
        short8v v = (short8v)0;
        if (rg < NN) v = *reinterpret_cast<const short8v*>(Ab + (size_t)rg * HH + k0 + c8 * 8);
        *reinterpret_cast<short8v*>(&As[r * LDR + c8 * 8]) = v;
      }
    } else {  // gather-mean of 5 rows of Tadd
#pragma unroll
      for (int e = tid; e < BM * (BK / 8); e += 256) {
        int r = e >> 3, c8 = e & 7;
        int rg = row0 + r;
        float a8[8] = {0.f, 0.f, 0.f, 0.f, 0.f, 0.f, 0.f, 0.f};
        if (rg < NN) {
#pragma unroll
          for (int j = 0; j < KNB; ++j) {
            int id = nbr[rg * KNB + j];
            short8v v = *reinterpret_cast<const short8v*>(Tadd + (size_t)id * HH + k0 + c8 * 8);
#pragma unroll
            for (int x = 0; x < 8; ++x) a8[x] += bf2f((unsigned short)v[x]);
          }
        }
        short8v o;
#pragma unroll
        for (int x = 0; x < 8; ++x) o[x] = (short)f2bf(a8[x] * 0.2f);
        *reinterpret_cast<short8v*>(&As[r * LDR + c8 * 8]) = o;
      }
    }
    // ---- stage B tile [128][BK] (bf16 weights, rows bn0..bn0+127) ----
#pragma unroll
    for (int e = tid; e < 128 * (BK / 8); e += 256) {
      int r = e >> 3, c8 = e & 7;
      short8v v = *reinterpret_cast<const short8v*>(Bw + (size_t)(bn0 + r) * KD + k0 + c8 * 8);
      *reinterpret_cast<short8v*>(&Bs[r * LDR + c8 * 8]) = v;
    }
    __syncthreads();

#pragma unroll
    for (int kk = 0; kk < BK / 32; ++kk) {
      int ko = kk * 32 + (lane >> 4) * 8;
      short8v a[4], b[4];
#pragma unroll
      for (int m = 0; m < 4; ++m)
        a[m] = *reinterpret_cast<const short8v*>(&As[(wr * 64 + m * 16 + (lane & 15)) * LDR + ko]);
#pragma unroll
      for (int n = 0; n < 4; ++n)
        b[n] = *reinterpret_cast<const short8v*>(&Bs[(wc * 64 + n * 16 + (lane & 15)) * LDR + ko]);
#pragma unroll
      for (int m = 0; m < 4; ++m)
#pragma unroll
        for (int n = 0; n < 4; ++n)
          acc[m][n] = __builtin_amdgcn_mfma_f32_16x16x32_bf16(a[m], b[n], acc[m][n], 0, 0, 0);
    }
    __syncthreads();
  }

  // ---- epilogue ----
  const int lr = (lane >> 4) * 4;
  const int lc = lane & 15;
#pragma unroll
  for (int m = 0; m < 4; ++m) {
#pragma unroll
    for (int i = 0; i < 4; ++i) {
      int rg = row0 + wr * 64 + m * 16 + lr + i;
      if (rg >= NN) continue;
#pragma unroll
      for (int n = 0; n < 4; ++n) {
        int col = bn0 + wc * 64 + n * 16 + lc;
        float v = acc[m][n][i] + bias[col];
        size_t off = (size_t)rg * HH + col;
        if constexpr (EPI >= 1)
          v += bf2f((unsigned short)Tadd[off]) + bf2f((unsigned short)Sadd[off]);
        if constexpr (EPI <= 1) {
          Cb[off] = (short)f2bf(v);
        } else if constexpr (EPI == 2) {
          Cf[off] = fmaxf(v, 0.f) * 0.5f;
        } else {
          Cf[off] = Cf[off] + fmaxf(v, 0.f) * 0.5f;
        }
      }
    }
  }
}

extern "C" void kernel_launch(void* const* d_in, const int* in_sizes, int n_in,
                              void* d_out, int out_size, void* d_ws, size_t ws_size,
                              hipStream_t stream) {
  const float* x0  = (const float*)d_in[0];
  const float* x1  = (const float*)d_in[1];
  const float* wh0 = (const float*)d_in[2];
  const float* bh0 = (const float*)d_in[3];
  const float* wh1 = (const float*)d_in[4];
  const float* bh1 = (const float*)d_in[5];
  const float* w0  = (const float*)d_in[6];
  const float* b0  = (const float*)d_in[7];
  const float* w1  = (const float*)d_in[8];
  const float* b1  = (const float*)d_in[9];
  const float* w2  = (const float*)d_in[10];
  const float* b2  = (const float*)d_in[11];
  const int* e0    = (const int*)d_in[12];
  const int* e1    = (const int*)d_in[13];
  const int* nbr0  = e0 + (size_t)NN * KNB;  // edge[1] row
  const int* nbr1  = e1 + (size_t)NN * KNB;
  float* out       = (float*)d_out;

  char* ws = (char*)d_ws;
  size_t off = 0;
  auto alloc = [&](size_t bytes) -> void* {
    off = (off + 255) & ~(size_t)255;
    void* p = ws + off;
    off += bytes;
    return p;
  };

  short* Wh0 = (short*)alloc((size_t)HH * DD * 2);
  short* Wh1 = (short*)alloc((size_t)HH * DD * 2);
  short* W0  = (short*)alloc((size_t)HH * HH * 2);
  short* W1  = (short*)alloc((size_t)HH * HH * 2);
  short* W2  = (short*)alloc((size_t)HH * HH * 2);
  const size_t NB = (size_t)NN * HH * 2;
  short* hi0 = (short*)alloc(NB);
  short* hi1 = (short*)alloc(NB);
  short* slf = (short*)alloc(NB);
  short* tb  = (short*)alloc(NB);
  short* hb  = (short*)alloc(NB);

  dim3 blk(256);
  dim3 gg((NN + 127) / 128, 2);

  // weight conversion
  {
    int n4 = (HH * DD) / 4;
    cvt_kernel<<<dim3((n4 + 255) / 256), blk, 0, stream>>>(wh0, Wh0, n4);
    cvt_kernel<<<dim3((n4 + 255) / 256), blk, 0, stream>>>(wh1, Wh1, n4);
    n4 = (HH * HH) / 4;
    cvt_kernel<<<dim3((n4 + 255) / 256), blk, 0, stream>>>(w0, W0, n4);
    cvt_kernel<<<dim3((n4 + 255) / 256), blk, 0, stream>>>(w1, W1, n4);
    cvt_kernel<<<dim3((n4 + 255) / 256), blk, 0, stream>>>(w2, W2, n4);
  }

  // h_init0 = Hin0(x0), h_init1 = Hin1(x1)
  gemm_k<DD, 0, 0><<<gg, blk, 0, stream>>>(x0, nullptr, Wh0, bh0, hi0, nullptr, nullptr, nullptr, nullptr);
  gemm_k<DD, 0, 0><<<gg, blk, 0, stream>>>(x1, nullptr, Wh1, bh1, hi1, nullptr, nullptr, nullptr, nullptr);

  // slf0 = w2(h_init1)
  gemm_k<HH, 1, 0><<<gg, blk, 0, stream>>>(nullptr, hi1, W2, b2, slf, nullptr, nullptr, nullptr, nullptr);

  // ---- view 0 ----
  gemm_k<HH, 1, 0><<<gg, blk, 0, stream>>>(nullptr, hi0, W0, b0, tb, nullptr, nullptr, nullptr, nullptr);
  gemm_k<HH, 2, 1><<<gg, blk, 0, stream>>>(nullptr, nullptr, W1, b1, hb, nullptr, tb, slf, nbr0);
  gemm_k<HH, 1, 0><<<gg, blk, 0, stream>>>(nullptr, hb, W0, b0, tb, nullptr, nullptr, nullptr, nullptr);
  gemm_k<HH, 2, 2><<<gg, blk, 0, stream>>>(nullptr, nullptr, W1, b1, nullptr, out, tb, slf, nbr0);

  // slf1 = w2(h_init0)  (slf buffer free now)
  gemm_k<HH, 1, 0><<<gg, blk, 0, stream>>>(nullptr, hi0, W2, b2, slf, nullptr, nullptr, nullptr, nullptr);

  // ---- view 1 ----
  gemm_k<HH, 1, 0><<<gg, blk, 0, stream>>>(nullptr, hi1, W0, b0, tb, nullptr, nullptr, nullptr, nullptr);
  gemm_k<HH, 2, 1><<<gg, blk, 0, stream>>>(nullptr, nullptr, W1, b1, hb, nullptr, tb, slf, nbr1);
  gemm_k<HH, 1, 0><<<gg, blk, 0, stream>>>(nullptr, hb, W0, b0, tb, nullptr, nullptr, nullptr, nullptr);
  gemm_k<HH, 2, 3><<<gg, blk, 0, stream>>>(nullptr, nullptr, W1, b1, nullptr, out, tb, slf, nbr1);

  (void)in_sizes; (void)n_in; (void)out_size; (void)ws_size;
}

// Round 2
// 763.171 us; speedup vs baseline: 1.6428x; 1.6428x over previous
//
#include <hip/hip_runtime.h>

#define NN 100000
#define DD 512
#define HH 256
#define KNB 5

typedef __attribute__((ext_vector_type(8))) short short8v;
typedef __attribute__((ext_vector_type(4))) short short4v;
typedef __attribute__((ext_vector_type(4))) float float4v;

static __device__ __forceinline__ float bf2f(unsigned short u) {
  union { unsigned int i; float f; } c;
  c.i = ((unsigned int)u) << 16;
  return c.f;
}
static __device__ __forceinline__ unsigned short f2bf(float f) {
  union { float f; unsigned int i; } c;
  c.f = f;
  unsigned int u = c.i;
  u += 0x7FFFu + ((u >> 16) & 1u);   // round-to-nearest-even
  return (unsigned short)(u >> 16);
}

// async global->LDS, 16B per lane; lds base must be wave-uniform
#define GLOAD16(g, l) __builtin_amdgcn_global_load_lds( \
    (const __attribute__((address_space(1))) unsigned int*)(g), \
    (__attribute__((address_space(3))) unsigned int*)(l), 16, 0, 0)

// fused fp32->bf16 conversion of all 5 weight matrices (one launch)
__global__ void cvt_all(const float* __restrict__ s0, short* __restrict__ d0,
                        const float* __restrict__ s1, short* __restrict__ d1,
                        const float* __restrict__ s2, short* __restrict__ d2,
                        const float* __restrict__ s3, short* __restrict__ d3,
                        const float* __restrict__ s4, short* __restrict__ d4) {
  const int S1 = (HH * DD) / 4;   // 32768 float4s per Hin weight
  const int S2 = (HH * HH) / 4;   // 16384 float4s per hidden weight
  int i = blockIdx.x * blockDim.x + threadIdx.x;
  const float* s; short* d; int j;
  if      (i < S1)            { s = s0; d = d0; j = i; }
  else if (i < 2*S1)          { s = s1; d = d1; j = i - S1; }
  else if (i < 2*S1 + S2)     { s = s2; d = d2; j = i - 2*S1; }
  else if (i < 2*S1 + 2*S2)   { s = s3; d = d3; j = i - 2*S1 - S2; }
  else if (i < 2*S1 + 3*S2)   { s = s4; d = d4; j = i - 2*S1 - 2*S2; }
  else return;
  float4 v = reinterpret_cast<const float4*>(s)[j];
  short4v o;
  o[0] = (short)f2bf(v.x); o[1] = (short)f2bf(v.y);
  o[2] = (short)f2bf(v.z); o[3] = (short)f2bf(v.w);
  reinterpret_cast<short4v*>(d)[j] = o;
}

// NT GEMM, BM=128 x BN=256(=HH) x BK=64, 8 waves (2M x 4N), per-wave 64x64.
// C[i][j] = sum_k A[i][k]*B[j][k] + bias[j] (+ epilogue)
// AMODE 0: A fp32 [NN][KD] staged as fp32 in LDS via global_load_lds, cvt on read
// AMODE 1: A bf16 [NN][HH] via global_load_lds
// AMODE 2: A[i] = mean_j Tadd[nbr[i*5+j]] (gather-mean, reg-staged)
// EPI 0: store bf16.  EPI 1: +=Tadd+Sadd, store bf16.
// EPI 2: +=Tadd+Sadd, relu, store bf16.  EPI 3: +=Tadd+Sadd, relu, avg w/ Fin -> fp32
template<int KD, int AMODE, int EPI>
__global__ __launch_bounds__(512, 4) void gemm_k(
    const float* __restrict__ Af, const short* __restrict__ Ab,
    const short* __restrict__ Bw, const float* __restrict__ bias,
    short* __restrict__ Cb, float* __restrict__ Cf,
    const short* __restrict__ Tadd, const short* __restrict__ Sadd,
    const short* __restrict__ Fin, const int* __restrict__ nbr)
{
  constexpr int BM = 128;
  constexpr int BK = 64;
  // B: [256][64] bf16, XOR-swizzled within each 128B row: phys_chunk = log_chunk ^ (row&7)
  __shared__ __align__(16) char BsRaw[256 * BK * 2];                       // 32 KB
  __shared__ __align__(16) char AsRaw[AMODE == 0 ? BM * BK * 4 : BM * BK * 2];

  const int tid = threadIdx.x;
  const int lane = tid & 63;
  const int wave = tid >> 6;
  const int wr = wave >> 2;      // 0..1  (M)
  const int wc = wave & 3;       // 0..3  (N)
  const int row0 = blockIdx.x * BM;

  float4v acc[4][4];
#pragma unroll
  for (int m = 0; m < 4; ++m)
#pragma unroll
    for (int n = 0; n < 4; ++n) acc[m][n] = (float4v)0.f;

  for (int k0 = 0; k0 < KD; k0 += BK) {
    // ---- stage B tile: 2048 16B-chunks, 4 per thread, pre-swizzled source ----
#pragma unroll
    for (int q = 0; q < 4; ++q) {
      int ch = q * 512 + tid;
      int r = ch >> 3, pc = ch & 7;
      int lc = pc ^ (r & 7);
      const short* g = Bw + (size_t)r * KD + k0 + lc * 8;
      GLOAD16(g, BsRaw + (q * 512 + wave * 64) * 16);
    }
    // ---- stage A tile ----
    if constexpr (AMODE == 0) {
      // fp32, [128][64]f32 = 32KB, rows are 256B = 16 chunks
#pragma unroll
      for (int q = 0; q < 4; ++q) {
        int ch = q * 512 + tid;
        int r = ch >> 4, pc = ch & 15;
        int lc = pc ^ (r & 15);
        int rg = min(row0 + r, NN - 1);
        const float* g = Af + (size_t)rg * KD + k0 + lc * 4;
        GLOAD16(g, AsRaw + (q * 512 + wave * 64) * 16);
      }
    } else if constexpr (AMODE == 1) {
#pragma unroll
      for (int q = 0; q < 2; ++q) {
        int ch = q * 512 + tid;
        int r = ch >> 3, pc = ch & 7;
        int lc = pc ^ (r & 7);
        int rg = min(row0 + r, NN - 1);
        const short* g = Ab + (size_t)rg * HH + k0 + lc * 8;
        GLOAD16(g, AsRaw + (q * 512 + wave * 64) * 16);
      }
    } else {
      // gather-mean of 5 rows of Tadd, reg-staged into swizzled LDS
#pragma unroll
      for (int q = 0; q < 2; ++q) {
        int ch = q * 512 + tid;
        int r = ch >> 3, pc = ch & 7;
        int lc = pc ^ (r & 7);
        int rg = min(row0 + r, NN - 1);
        float a8[8] = {0.f, 0.f, 0.f, 0.f, 0.f, 0.f, 0.f, 0.f};
#pragma unroll
        for (int j = 0; j < KNB; ++j) {
          int id = nbr[rg * KNB + j];
          short8v v = *reinterpret_cast<const short8v*>(Tadd + (size_t)id * HH + k0 + lc * 8);
#pragma unroll
          for (int x = 0; x < 8; ++x) a8[x] += bf2f((unsigned short)v[x]);
        }
        short8v o;
#pragma unroll
        for (int x = 0; x < 8; ++x) o[x] = (short)f2bf(a8[x] * 0.2f);
        *reinterpret_cast<short8v*>(AsRaw + ch * 16) = o;
      }
    }
    __syncthreads();

    // ---- compute ----
#pragma unroll
    for (int kk = 0; kk < 2; ++kk) {
      const int ckb = kk * 4 + (lane >> 4);     // logical 16B-chunk within row (bf16)
      short8v a[4], b[4];
#pragma unroll
      for (int n = 0; n < 4; ++n) {
        int rb = wc * 64 + n * 16 + (lane & 15);
        b[n] = *reinterpret_cast<const short8v*>(BsRaw + rb * 128 + ((ckb ^ (rb & 7)) << 4));
      }
      if constexpr (AMODE == 0) {
#pragma unroll
        for (int m = 0; m < 4; ++m) {
          int ra = wr * 64 + m * 16 + (lane & 15);
          int ck0 = kk * 8 + (lane >> 4) * 2;   // fp32 rows: 16 chunks
          float4v f0 = *reinterpret_cast<const float4v*>(AsRaw + ra * 256 + ((ck0 ^ (ra & 15)) << 4));
          float4v f1 = *reinterpret_cast<const float4v*>(AsRaw + ra * 256 + (((ck0 + 1) ^ (ra & 15)) << 4));
          short8v av;
          av[0] = (short)f2bf(f0[0]); av[1] = (short)f2bf(f0[1]);
          av[2] = (short)f2bf(f0[2]); av[3] = (short)f2bf(f0[3]);
          av[4] = (short)f2bf(f1[0]); av[5] = (short)f2bf(f1[1]);
          av[6] = (short)f2bf(f1[2]); av[7] = (short)f2bf(f1[3]);
          a[m] = av;
        }
      } else {
#pragma unroll
        for (int m = 0; m < 4; ++m) {
          int ra = wr * 64 + m * 16 + (lane & 15);
          a[m] = *reinterpret_cast<const short8v*>(AsRaw + ra * 128 + ((ckb ^ (ra & 7)) << 4));
        }
      }
#pragma unroll
      for (int m = 0; m < 4; ++m)
#pragma unroll
        for (int n = 0; n < 4; ++n)
          acc[m][n] = __builtin_amdgcn_mfma_f32_16x16x32_bf16(b[n], a[m], acc[m][n], 0, 0, 0);
          // swapped operands: lane's 4 acc elems = 4 CONSECUTIVE COLUMNS of C, one row
    }
    __syncthreads();
  }

  // ---- epilogue: row = .. + (lane&15), cols = colb..colb+3 -> vectorized ----
  const int crow = lane & 15;
  const int cg = (lane >> 4) * 4;
#pragma unroll
  for (int m = 0; m < 4; ++m) {
    int rg = row0 + wr * 64 + m * 16 + crow;
    if (rg >= NN) continue;
#pragma unroll
    for (int n = 0; n < 4; ++n) {
      int colb = wc * 64 + n * 16 + cg;
      size_t off = (size_t)rg * HH + colb;
      float4v bi = *reinterpret_cast<const float4v*>(bias + colb);
      float v[4];
#pragma unroll
      for (int i = 0; i < 4; ++i) v[i] = acc[m][n][i] + bi[i];
      if constexpr (EPI >= 1) {
        short4v t4 = *reinterpret_cast<const short4v*>(Tadd + off);
        short4v s4 = *reinterpret_cast<const short4v*>(Sadd + off);
#pragma unroll
        for (int i = 0; i < 4; ++i)
          v[i] += bf2f((unsigned short)t4[i]) + bf2f((unsigned short)s4[i]);
      }
      if constexpr (EPI >= 2) {
#pragma unroll
        for (int i = 0; i < 4; ++i) v[i] = fmaxf(v[i], 0.f);
      }
      if constexpr (EPI <= 2) {
        short4v o;
#pragma unroll
        for (int i = 0; i < 4; ++i) o[i] = (short)f2bf(v[i]);
        *reinterpret_cast<short4v*>(Cb + off) = o;
      } else {
        short4v f4 = *reinterpret_cast<const short4v*>(Fin + off);
        float4v o;
#pragma unroll
        for (int i = 0; i < 4; ++i) o[i] = (v[i] + bf2f((unsigned short)f4[i])) * 0.5f;
        *reinterpret_cast<float4v*>(Cf + off) = o;
      }
    }
  }
}

extern "C" void kernel_launch(void* const* d_in, const int* in_sizes, int n_in,
                              void* d_out, int out_size, void* d_ws, size_t ws_size,
                              hipStream_t stream) {
  const float* x0  = (const float*)d_in[0];
  const float* x1  = (const float*)d_in[1];
  const float* wh0 = (const float*)d_in[2];
  const float* bh0 = (const float*)d_in[3];
  const float* wh1 = (const float*)d_in[4];
  const float* bh1 = (const float*)d_in[5];
  const float* w0  = (const float*)d_in[6];
  const float* b0  = (const float*)d_in[7];
  const float* w1  = (const float*)d_in[8];
  const float* b1  = (const float*)d_in[9];
  const float* w2  = (const float*)d_in[10];
  const float* b2  = (const float*)d_in[11];
  const int* e0    = (const int*)d_in[12];
  const int* e1    = (const int*)d_in[13];
  const int* nbr0  = e0 + (size_t)NN * KNB;  // edge[1]
  const int* nbr1  = e1 + (size_t)NN * KNB;
  float* out       = (float*)d_out;

  char* ws = (char*)d_ws;
  size_t off = 0;
  auto alloc = [&](size_t bytes) -> void* {
    off = (off + 255) & ~(size_t)255;
    void* p = ws + off;
    off += bytes;
    return p;
  };

  short* Wh0 = (short*)alloc((size_t)HH * DD * 2);
  short* Wh1 = (short*)alloc((size_t)HH * DD * 2);
  short* W0  = (short*)alloc((size_t)HH * HH * 2);
  short* W1  = (short*)alloc((size_t)HH * HH * 2);
  short* W2  = (short*)alloc((size_t)HH * HH * 2);
  const size_t NB = (size_t)NN * HH * 2;
  short* hi0 = (short*)alloc(NB);
  short* hi1 = (short*)alloc(NB);
  short* slf = (short*)alloc(NB);
  short* tb  = (short*)alloc(NB);
  short* hb  = (short*)alloc(NB);

  // one fused weight-conversion launch
  {
    int total4 = 2 * (HH * DD / 4) + 3 * (HH * HH / 4);  // 114688
    cvt_all<<<dim3((total4 + 255) / 256), dim3(256), 0, stream>>>(
        wh0, Wh0, wh1, Wh1, w0, W0, w1, W1, w2, W2);
  }

  dim3 blk(512);
  dim3 gg((NN + 127) / 128);  // 782 blocks, BN=256 covers all of HH

  // projections
  gemm_k<DD, 0, 0><<<gg, blk, 0, stream>>>(x0, nullptr, Wh0, bh0, hi0, nullptr, nullptr, nullptr, nullptr, nullptr);
  gemm_k<DD, 0, 0><<<gg, blk, 0, stream>>>(x1, nullptr, Wh1, bh1, hi1, nullptr, nullptr, nullptr, nullptr, nullptr);

  // ---- view 0 ----
  gemm_k<HH, 1, 0><<<gg, blk, 0, stream>>>(nullptr, hi1, W2, b2, slf, nullptr, nullptr, nullptr, nullptr, nullptr);
  gemm_k<HH, 1, 0><<<gg, blk, 0, stream>>>(nullptr, hi0, W0, b0, tb, nullptr, nullptr, nullptr, nullptr, nullptr);
  gemm_k<HH, 2, 1><<<gg, blk, 0, stream>>>(nullptr, nullptr, W1, b1, hb, nullptr, tb, slf, nullptr, nbr0);
  gemm_k<HH, 1, 0><<<gg, blk, 0, stream>>>(nullptr, hb, W0, b0, tb, nullptr, nullptr, nullptr, nullptr, nullptr);
  // fin0 = relu(...) -> bf16, stored into hb (hb dead in this launch)
  gemm_k<HH, 2, 2><<<gg, blk, 0, stream>>>(nullptr, nullptr, W1, b1, hb, nullptr, tb, slf, nullptr, nbr0);

  // ---- view 1 ----
  gemm_k<HH, 1, 0><<<gg, blk, 0, stream>>>(nullptr, hi0, W2, b2, slf, nullptr, nullptr, nullptr, nullptr, nullptr);
  gemm_k<HH, 1, 0><<<gg, blk, 0, stream>>>(nullptr, hi1, W0, b0, tb, nullptr, nullptr, nullptr, nullptr, nullptr);
  gemm_k<HH, 2, 1><<<gg, blk, 0, stream>>>(nullptr, nullptr, W1, b1, hi0, nullptr, tb, slf, nullptr, nbr1);
  gemm_k<HH, 1, 0><<<gg, blk, 0, stream>>>(nullptr, hi0, W0, b0, tb, nullptr, nullptr, nullptr, nullptr, nullptr);
  // out = 0.5*(relu(...) + fin0)
  gemm_k<HH, 2, 3><<<gg, blk, 0, stream>>>(nullptr, nullptr, W1, b1, nullptr, out, tb, slf, hb, nbr1);

  (void)in_sizes; (void)n_in; (void)out_size; (void)ws_size;
}

// Round 3
// 540.508 us; speedup vs baseline: 2.3196x; 1.4120x over previous
//
#include <hip/hip_runtime.h>

#define NN 100000
#define DD 512
#define HH 256
#define KNB 5

typedef __attribute__((ext_vector_type(8))) short short8v;
typedef __attribute__((ext_vector_type(4))) short short4v;
typedef __attribute__((ext_vector_type(4))) float float4v;

static __device__ __forceinline__ float bf2f(unsigned short u) {
  union { unsigned int i; float f; } c;
  c.i = ((unsigned int)u) << 16;
  return c.f;
}
static __device__ __forceinline__ unsigned short f2bf(float f) {
  union { float f; unsigned int i; } c;
  c.f = f;
  unsigned int u = c.i;
  u += 0x7FFFu + ((u >> 16) & 1u);   // round-to-nearest-even
  return (unsigned short)(u >> 16);
}

// async global->LDS, 16B per lane; lds base must be wave-uniform
#define GLOAD16(g, l) __builtin_amdgcn_global_load_lds( \
    (const __attribute__((address_space(1))) unsigned int*)(g), \
    (__attribute__((address_space(3))) unsigned int*)(l), 16, 0, 0)

// bf16 conversion of the two input-projection weights
__global__ void cvt2(const float* __restrict__ s0, short* __restrict__ d0,
                     const float* __restrict__ s1, short* __restrict__ d1) {
  const int S1 = (HH * DD) / 4;   // 32768 float4s each
  int i = blockIdx.x * blockDim.x + threadIdx.x;
  if (i >= 2 * S1) return;
  const float* s = (i < S1) ? s0 : s1;
  short* d = (i < S1) ? d0 : d1;
  int j = (i < S1) ? i : i - S1;
  float4 v = reinterpret_cast<const float4*>(s)[j];
  short4v o;
  o[0] = (short)f2bf(v.x); o[1] = (short)f2bf(v.y);
  o[2] = (short)f2bf(v.z); o[3] = (short)f2bf(v.w);
  reinterpret_cast<short4v*>(d)[j] = o;
}

// Build Bcat [256][768] = [w0 | W01=w1@w0 | w2] in bf16, and fused bias
// bc[i] = b0[i] + b1[i] + b2[i] + sum_k w1[i][k]*b0[k]   (all fp32 math)
__global__ void prep_w01(const float* __restrict__ w0, const float* __restrict__ w1,
                         const float* __restrict__ w2, const float* __restrict__ b0,
                         const float* __restrict__ b1, const float* __restrict__ b2,
                         short* __restrict__ Bcat, float* __restrict__ bc) {
  int i = blockIdx.x;      // output row 0..255
  int j = threadIdx.x;     // col 0..255
  Bcat[(size_t)i * 768 + j]       = (short)f2bf(w0[i * 256 + j]);
  Bcat[(size_t)i * 768 + 512 + j] = (short)f2bf(w2[i * 256 + j]);
  float acc = 0.f;
  for (int k = 0; k < 256; ++k)
    acc = fmaf(w1[i * 256 + k], w0[k * 256 + j], acc);
  Bcat[(size_t)i * 768 + 256 + j] = (short)f2bf(acc);
  if (j == 0) {
    float s = b0[i] + b1[i] + b2[i];
    for (int k = 0; k < 256; ++k) s = fmaf(w1[i * 256 + k], b0[k], s);
    bc[i] = s;
  }
}

// NT GEMM, BM=128 x BN=256(=HH) x BK=64, 8 waves (2M x 4N), per-wave 64x64.
// MODE 0: projection. A = Af fp32 [NN][KD], staged fp32 in LDS, cvt on read.
// MODE 1: fused epoch, KD=768 concat-K:
//   k in [0,256)   : dense bf16 rows of Hin
//   k in [256,512) : A[i] = mean_j Hin[nbr[i*5+j]]  (gather-mean, reg-staged)
//   k in [512,768) : dense bf16 rows of Hoth
// EPI 0: store bf16.  EPI 2: relu, store bf16.  EPI 3: relu, avg with Fin -> fp32.
template<int KD, int MODE, int EPI>
__global__ __launch_bounds__(512, 4) void gemm_k(
    const float* __restrict__ Af, const short* __restrict__ Hin,
    const short* __restrict__ Hoth, const short* __restrict__ Bw,
    const float* __restrict__ bias, short* __restrict__ Cb,
    float* __restrict__ Cf, const short* __restrict__ Fin,
    const int* __restrict__ nbr)
{
  constexpr int BM = 128;
  constexpr int BK = 64;
  // B: [256][64] bf16, XOR-swizzled per 128B row: phys_chunk = log_chunk ^ (row&7)
  __shared__ __align__(16) char BsRaw[256 * BK * 2];                       // 32 KB
  __shared__ __align__(16) char AsRaw[MODE == 0 ? BM * BK * 4 : BM * BK * 2];
  __shared__ int nbrL[MODE == 1 ? BM * KNB : 4];

  const int tid = threadIdx.x;
  const int lane = tid & 63;
  const int wave = tid >> 6;
  const int wr = wave >> 2;      // 0..1  (M)
  const int wc = wave & 3;       // 0..3  (N)
  const int row0 = blockIdx.x * BM;

  if constexpr (MODE == 1) {
    // preload this block's neighbor indices once (read 4x per kernel otherwise)
    for (int e = tid; e < BM * KNB; e += 512) {
      int r = e / KNB;
      int rg = min(row0 + r, NN - 1);
      nbrL[e] = nbr[rg * KNB + (e - r * KNB)];
    }
    // writes complete before first gather use (k0=256) -- several barriers earlier
  }

  float4v acc[4][4];
#pragma unroll
  for (int m = 0; m < 4; ++m)
#pragma unroll
    for (int n = 0; n < 4; ++n) acc[m][n] = (float4v)0.f;

  for (int k0 = 0; k0 < KD; k0 += BK) {
    // ---- stage B tile: 2048 16B-chunks, pre-swizzled source ----
#pragma unroll
    for (int q = 0; q < 4; ++q) {
      int ch = q * 512 + tid;
      int r = ch >> 3, pc = ch & 7;
      int lc = pc ^ (r & 7);
      GLOAD16(Bw + (size_t)r * KD + k0 + lc * 8, BsRaw + (q * 512 + wave * 64) * 16);
    }
    // ---- stage A tile ----
    if constexpr (MODE == 0) {
      // fp32 [128][64] = 32KB, rows 256B = 16 chunks
#pragma unroll
      for (int q = 0; q < 4; ++q) {
        int ch = q * 512 + tid;
        int r = ch >> 4, pc = ch & 15;
        int lc = pc ^ (r & 15);
        int rg = min(row0 + r, NN - 1);
        GLOAD16(Af + (size_t)rg * KD + k0 + lc * 4, AsRaw + (q * 512 + wave * 64) * 16);
      }
    } else {
      if (k0 < 256 || k0 >= 512) {
        const short* H = (k0 < 256) ? (Hin + k0) : (Hoth + (k0 - 512));
#pragma unroll
        for (int q = 0; q < 2; ++q) {
          int ch = q * 512 + tid;
          int r = ch >> 3, pc = ch & 7;
          int lc = pc ^ (r & 7);
          int rg = min(row0 + r, NN - 1);
          GLOAD16(H + (size_t)rg * HH + lc * 8, AsRaw + (q * 512 + wave * 64) * 16);
        }
      } else {
        const int kb = k0 - 256;
#pragma unroll
        for (int q = 0; q < 2; ++q) {
          int ch = q * 512 + tid;
          int r = ch >> 3, pc = ch & 7;
          int lc = pc ^ (r & 7);
          float a8[8] = {0.f, 0.f, 0.f, 0.f, 0.f, 0.f, 0.f, 0.f};
#pragma unroll
          for (int j = 0; j < KNB; ++j) {
            int id = nbrL[r * KNB + j];
            short8v v = *reinterpret_cast<const short8v*>(Hin + (size_t)id * HH + kb + lc * 8);
#pragma unroll
            for (int x = 0; x < 8; ++x) a8[x] += bf2f((unsigned short)v[x]);
          }
          short8v o;
#pragma unroll
          for (int x = 0; x < 8; ++x) o[x] = (short)f2bf(a8[x] * 0.2f);
          *reinterpret_cast<short8v*>(AsRaw + ch * 16) = o;
        }
      }
    }
    __syncthreads();

    // ---- compute ----
#pragma unroll
    for (int kk = 0; kk < 2; ++kk) {
      const int ckb = kk * 4 + (lane >> 4);     // logical 16B chunk in bf16 row
      short8v a[4], b[4];
#pragma unroll
      for (int n = 0; n < 4; ++n) {
        int rb = wc * 64 + n * 16 + (lane & 15);
        b[n] = *reinterpret_cast<const short8v*>(BsRaw + rb * 128 + ((ckb ^ (rb & 7)) << 4));
      }
      if constexpr (MODE == 0) {
#pragma unroll
        for (int m = 0; m < 4; ++m) {
          int ra = wr * 64 + m * 16 + (lane & 15);
          int ck0 = kk * 8 + (lane >> 4) * 2;   // fp32 rows: 16 chunks
          float4v f0 = *reinterpret_cast<const float4v*>(AsRaw + ra * 256 + ((ck0 ^ (ra & 15)) << 4));
          float4v f1 = *reinterpret_cast<const float4v*>(AsRaw + ra * 256 + (((ck0 + 1) ^ (ra & 15)) << 4));
          short8v av;
          av[0] = (short)f2bf(f0[0]); av[1] = (short)f2bf(f0[1]);
          av[2] = (short)f2bf(f0[2]); av[3] = (short)f2bf(f0[3]);
          av[4] = (short)f2bf(f1[0]); av[5] = (short)f2bf(f1[1]);
          av[6] = (short)f2bf(f1[2]); av[7] = (short)f2bf(f1[3]);
          a[m] = av;
        }
      } else {
#pragma unroll
        for (int m = 0; m < 4; ++m) {
          int ra = wr * 64 + m * 16 + (lane & 15);
          a[m] = *reinterpret_cast<const short8v*>(AsRaw + ra * 128 + ((ckb ^ (ra & 7)) << 4));
        }
      }
#pragma unroll
      for (int m = 0; m < 4; ++m)
#pragma unroll
        for (int n = 0; n < 4; ++n)
          acc[m][n] = __builtin_amdgcn_mfma_f32_16x16x32_bf16(b[n], a[m], acc[m][n], 0, 0, 0);
          // swapped operands: lane's 4 acc elems = 4 consecutive C columns of one row
    }
    __syncthreads();
  }

  // ---- epilogue (vectorized: 4 consecutive cols per lane) ----
  const int crow = lane & 15;
  const int cg = (lane >> 4) * 4;
#pragma unroll
  for (int m = 0; m < 4; ++m) {
    int rg = row0 + wr * 64 + m * 16 + crow;
    if (rg >= NN) continue;
#pragma unroll
    for (int n = 0; n < 4; ++n) {
      int colb = wc * 64 + n * 16 + cg;
      size_t off = (size_t)rg * HH + colb;
      float4v bi = *reinterpret_cast<const float4v*>(bias + colb);
      float v[4];
#pragma unroll
      for (int i = 0; i < 4; ++i) v[i] = acc[m][n][i] + bi[i];
      if constexpr (EPI >= 2) {
#pragma unroll
        for (int i = 0; i < 4; ++i) v[i] = fmaxf(v[i], 0.f);
      }
      if constexpr (EPI <= 2) {
        short4v o;
#pragma unroll
        for (int i = 0; i < 4; ++i) o[i] = (short)f2bf(v[i]);
        *reinterpret_cast<short4v*>(Cb + off) = o;
      } else {
        short4v f4 = *reinterpret_cast<const short4v*>(Fin + off);
        float4v o;
#pragma unroll
        for (int i = 0; i < 4; ++i) o[i] = (v[i] + bf2f((unsigned short)f4[i])) * 0.5f;
        *reinterpret_cast<float4v*>(Cf + off) = o;
      }
    }
  }
}

extern "C" void kernel_launch(void* const* d_in, const int* in_sizes, int n_in,
                              void* d_out, int out_size, void* d_ws, size_t ws_size,
                              hipStream_t stream) {
  const float* x0  = (const float*)d_in[0];
  const float* x1  = (const float*)d_in[1];
  const float* wh0 = (const float*)d_in[2];
  const float* bh0 = (const float*)d_in[3];
  const float* wh1 = (const float*)d_in[4];
  const float* bh1 = (const float*)d_in[5];
  const float* w0  = (const float*)d_in[6];
  const float* b0  = (const float*)d_in[7];
  const float* w1  = (const float*)d_in[8];
  const float* b1  = (const float*)d_in[9];
  const float* w2  = (const float*)d_in[10];
  const float* b2  = (const float*)d_in[11];
  const int* e0    = (const int*)d_in[12];
  const int* e1    = (const int*)d_in[13];
  const int* nbr0  = e0 + (size_t)NN * KNB;  // edge[1]
  const int* nbr1  = e1 + (size_t)NN * KNB;
  float* out       = (float*)d_out;

  char* ws = (char*)d_ws;
  size_t off = 0;
  auto alloc = [&](size_t bytes) -> void* {
    off = (off + 255) & ~(size_t)255;
    void* p = ws + off;
    off += bytes;
    return p;
  };

  short* Wh0  = (short*)alloc((size_t)HH * DD * 2);
  short* Wh1  = (short*)alloc((size_t)HH * DD * 2);
  short* Bcat = (short*)alloc((size_t)HH * 768 * 2);
  float* bc   = (float*)alloc((size_t)HH * 4);
  const size_t NB = (size_t)NN * HH * 2;
  short* hi0 = (short*)alloc(NB);
  short* hi1 = (short*)alloc(NB);
  short* hb  = (short*)alloc(NB);
  short* f0  = (short*)alloc(NB);

  // weight prep
  cvt2<<<dim3(256), dim3(256), 0, stream>>>(wh0, Wh0, wh1, Wh1);
  prep_w01<<<dim3(256), dim3(256), 0, stream>>>(w0, w1, w2, b0, b1, b2, Bcat, bc);

  dim3 blk(512);
  dim3 gg((NN + 127) / 128);  // 782 blocks

  // projections: hi_v = Hin_v(x_v)
  gemm_k<DD, 0, 0><<<gg, blk, 0, stream>>>(x0, nullptr, nullptr, Wh0, bh0, hi0, nullptr, nullptr, nullptr);
  gemm_k<DD, 0, 0><<<gg, blk, 0, stream>>>(x1, nullptr, nullptr, Wh1, bh1, hi1, nullptr, nullptr, nullptr);

  // view 0: two fused epochs
  gemm_k<768, 1, 0><<<gg, blk, 0, stream>>>(nullptr, hi0, hi1, Bcat, bc, hb, nullptr, nullptr, nbr0);
  gemm_k<768, 1, 2><<<gg, blk, 0, stream>>>(nullptr, hb, hi1, Bcat, bc, f0, nullptr, nullptr, nbr0);

  // view 1: two fused epochs (hb reused), final averages with f0
  gemm_k<768, 1, 0><<<gg, blk, 0, stream>>>(nullptr, hi1, hi0, Bcat, bc, hb, nullptr, nullptr, nbr1);
  gemm_k<768, 1, 3><<<gg, blk, 0, stream>>>(nullptr, hb, hi0, Bcat, bc, nullptr, out, f0, nbr1);

  (void)in_sizes; (void)n_in; (void)out_size; (void)ws_size;
}